// Round 1
// baseline (344.766 us; speedup 1.0000x reference)
//
#include <hip/hip_runtime.h>
#include <hip/hip_bf16.h>

#define B_ 2
#define S_ 2048
#define D_ 1024
#define H_ 16
#define DH 64
#define M_ (B_*S_)  // 4096

using bf16x8 = __attribute__((ext_vector_type(8))) __bf16;
using f32x4  = __attribute__((ext_vector_type(4))) float;

// ---------------- QKV projection GEMM ----------------
// C[m][n] = sum_k x[m][k] * W[k][n] + bias[n], output scaled (Q only) and
// written as bf16 to ws in [B][H][S][dh] layout.
__global__ __launch_bounds__(256) void qkv_gemm(
    const float* __restrict__ x,
    const float* __restrict__ Wq, const float* __restrict__ bq,
    const float* __restrict__ Wk, const float* __restrict__ bk,
    const float* __restrict__ Wv, const float* __restrict__ bv,
    __bf16* __restrict__ wsq, __bf16* __restrict__ wsk, __bf16* __restrict__ wsv)
{
    const int z = blockIdx.z;
    const float* __restrict__ W    = (z == 0) ? Wq : (z == 1) ? Wk : Wv;
    const float* __restrict__ bias = (z == 0) ? bq : (z == 1) ? bk : bv;
    __bf16* __restrict__ out       = (z == 0) ? wsq : (z == 1) ? wsk : wsv;
    const float scale = (z == 0) ? 0.125f : 1.0f;  // 1/sqrt(64) folded into Q

    // A tile 128x32, B tile stored transposed as [n][k] 128x32. XOR swizzle on
    // 16B slots (element bits 3..4) keyed by row bits 1..2 -> ~2-way conflicts.
    __shared__ __bf16 Al[128 * 32];
    __shared__ __bf16 Bl[128 * 32];

    const int tid  = threadIdx.x;
    const int lane = tid & 63;
    const int w    = tid >> 6;
    const int m0   = blockIdx.y * 128;
    const int n0   = blockIdx.x * 128;
    const int wr   = (w >> 1) * 64;
    const int wc   = (w & 1) * 64;

    f32x4 acc[4][4] = {};

    for (int kt = 0; kt < D_ / 32; ++kt) {
        const int k0 = kt * 32;
        // stage A (x): 128 rows x 32 k, fp32 -> bf16
        #pragma unroll
        for (int i = 0; i < 16; ++i) {
            int idx = i * 256 + tid;
            int am = idx >> 5, ak = idx & 31;
            Al[am * 32 + (ak ^ (((am >> 1) & 3) << 3))] =
                (__bf16)x[(size_t)(m0 + am) * D_ + k0 + ak];
        }
        // stage B: W[k][n] -> Bl[n][k]
        #pragma unroll
        for (int i = 0; i < 16; ++i) {
            int idx = i * 256 + tid;
            int bk_ = idx >> 7, bn = idx & 127;
            Bl[bn * 32 + (bk_ ^ (((bn >> 1) & 3) << 3))] =
                (__bf16)W[(size_t)(k0 + bk_) * D_ + n0 + bn];
        }
        __syncthreads();

        bf16x8 af[4], bfr[4];
        #pragma unroll
        for (int mi = 0; mi < 4; ++mi) {
            int row = wr + mi * 16 + (lane & 15);
            af[mi] = *(const bf16x8*)&Al[row * 32 + (((lane >> 4) * 8) ^ (((row >> 1) & 3) << 3))];
        }
        #pragma unroll
        for (int ni = 0; ni < 4; ++ni) {
            int col = wc + ni * 16 + (lane & 15);
            bfr[ni] = *(const bf16x8*)&Bl[col * 32 + (((lane >> 4) * 8) ^ (((col >> 1) & 3) << 3))];
        }
        #pragma unroll
        for (int mi = 0; mi < 4; ++mi)
            #pragma unroll
            for (int ni = 0; ni < 4; ++ni)
                acc[mi][ni] = __builtin_amdgcn_mfma_f32_16x16x32_bf16(
                    af[mi], bfr[ni], acc[mi][ni], 0, 0, 0);
        __syncthreads();
    }

    // epilogue: C/D layout col = lane&15, row = (lane>>4)*4 + r (m89-verified)
    #pragma unroll
    for (int mi = 0; mi < 4; ++mi) {
        #pragma unroll
        for (int ni = 0; ni < 4; ++ni) {
            int col = n0 + wc + ni * 16 + (lane & 15);
            int h = col >> 6, dh = col & 63;
            float bv_ = bias[col];
            #pragma unroll
            for (int r = 0; r < 4; ++r) {
                int row = m0 + wr + mi * 16 + (lane >> 4) * 4 + r;
                int b = row >> 11, s = row & 2047;
                float v = (acc[mi][ni][r] + bv_) * scale;
                out[((size_t)(b * H_ + h) * S_ + s) * DH + dh] = (__bf16)v;
            }
        }
    }
}

// ---------------- flash attention (causal) ----------------
// grid = (S/64, H, B), 4 waves; wave w owns q rows [q0+16w, q0+16w+16).
__global__ __launch_bounds__(256) void attn(
    const __bf16* __restrict__ Q, const __bf16* __restrict__ K,
    const __bf16* __restrict__ V, float* __restrict__ out)
{
    __shared__ __bf16 Kl[64 * 64];       // [kv][dh], swizzled
    __shared__ __bf16 Vt[64 * 64];       // [dh][kv], swizzled
    __shared__ __bf16 Pl[4][16 * 64];    // per-wave P, [qrow][kv], swizzled

    const int tid = threadIdx.x, lane = tid & 63, w = tid >> 6;
    const int q0 = blockIdx.x * 64;
    const int h = blockIdx.y, b = blockIdx.z;
    const size_t base = ((size_t)(b * H_ + h)) * S_ * DH;
    const __bf16* __restrict__ Qg = Q + base;
    const __bf16* __restrict__ Kg = K + base;
    const __bf16* __restrict__ Vg = V + base;

    // Q fragments in registers (A-layout: row = lane&15, k contiguous 8)
    const int qrow = q0 + w * 16 + (lane & 15);
    bf16x8 aq[2];
    #pragma unroll
    for (int kk = 0; kk < 2; ++kk)
        aq[kk] = *(const bf16x8*)&Qg[(size_t)qrow * DH + kk * 32 + (lane >> 4) * 8];

    f32x4 accO[4] = {};
    float mrow[4], lrow[4];
    #pragma unroll
    for (int r = 0; r < 4; ++r) { mrow[r] = -1e30f; lrow[r] = 0.f; }

    const int nkv = q0 / 64 + 1;
    for (int kt = 0; kt < nkv; ++kt) {
        const int kv0 = kt * 64;
        // stage K [kv][dh] and V transposed [dh][kv]
        #pragma unroll
        for (int i = 0; i < 2; ++i) {
            int e = (i * 256 + tid) * 8;
            int kv = e >> 6, d0 = e & 63;
            bf16x8 k8 = *(const bf16x8*)&Kg[(size_t)(kv0 + kv) * DH + d0];
            *(bf16x8*)&Kl[kv * 64 + (d0 ^ ((kv & 7) << 3))] = k8;
            bf16x8 v8 = *(const bf16x8*)&Vg[(size_t)(kv0 + kv) * DH + d0];
            #pragma unroll
            for (int j = 0; j < 8; ++j)
                Vt[(d0 + j) * 64 + (kv ^ (((d0 + j) & 7) << 3))] = v8[j];
        }
        __syncthreads();

        // S = Q K^T, 4 kv-fragments of 16
        f32x4 sf[4];
        #pragma unroll
        for (int f = 0; f < 4; ++f) {
            f32x4 zacc = {};
            #pragma unroll
            for (int kk = 0; kk < 2; ++kk) {
                int col = f * 16 + (lane & 15);  // kv column
                bf16x8 bk = *(const bf16x8*)&Kl[col * 64 +
                    ((kk * 32 + (lane >> 4) * 8) ^ ((col & 7) << 3))];
                zacc = __builtin_amdgcn_mfma_f32_16x16x32_bf16(aq[kk], bk, zacc, 0, 0, 0);
            }
            sf[f] = zacc;
        }

        // causal mask: only the diagonal tile needs it (tiles are 64-aligned)
        if (kv0 == q0) {
            #pragma unroll
            for (int f = 0; f < 4; ++f) {
                int kvg = kv0 + f * 16 + (lane & 15);
                #pragma unroll
                for (int r = 0; r < 4; ++r) {
                    int qg = q0 + w * 16 + (lane >> 4) * 4 + r;
                    if (kvg > qg) sf[f][r] = -1e30f;
                }
            }
        }

        // online softmax (row = q lives across the 16-lane group dimension)
        float alpha[4];
        #pragma unroll
        for (int r = 0; r < 4; ++r) {
            float mx = fmaxf(fmaxf(sf[0][r], sf[1][r]), fmaxf(sf[2][r], sf[3][r]));
            #pragma unroll
            for (int off = 8; off >= 1; off >>= 1)
                mx = fmaxf(mx, __shfl_xor(mx, off, 64));
            float mnew = fmaxf(mrow[r], mx);
            alpha[r] = __expf(mrow[r] - mnew);
            mrow[r] = mnew;
            float rs = 0.f;
            #pragma unroll
            for (int f = 0; f < 4; ++f) {
                float p = __expf(sf[f][r] - mnew);
                sf[f][r] = p;
                rs += p;
            }
            #pragma unroll
            for (int off = 8; off >= 1; off >>= 1)
                rs += __shfl_xor(rs, off, 64);
            lrow[r] = lrow[r] * alpha[r] + rs;
        }

        // P (C-layout) -> per-wave LDS -> A-layout fragments
        #pragma unroll
        for (int f = 0; f < 4; ++f)
            #pragma unroll
            for (int r = 0; r < 4; ++r) {
                int row = (lane >> 4) * 4 + r;
                int c = f * 16 + (lane & 15);
                Pl[w][row * 64 + (c ^ ((row & 7) << 3))] = (__bf16)sf[f][r];
            }

        #pragma unroll
        for (int f = 0; f < 4; ++f)
            #pragma unroll
            for (int r = 0; r < 4; ++r)
                accO[f][r] *= alpha[r];

        // O += P V  (A = P, B = V via transposed Vt)
        #pragma unroll
        for (int kk = 0; kk < 2; ++kk) {
            int prow = lane & 15;
            bf16x8 pa = *(const bf16x8*)&Pl[w][prow * 64 +
                ((kk * 32 + (lane >> 4) * 8) ^ ((prow & 7) << 3))];
            #pragma unroll
            for (int f = 0; f < 4; ++f) {
                int vrow = f * 16 + (lane & 15);  // dh
                bf16x8 vb = *(const bf16x8*)&Vt[vrow * 64 +
                    ((kk * 32 + (lane >> 4) * 8) ^ ((vrow & 7) << 3))];
                accO[f] = __builtin_amdgcn_mfma_f32_16x16x32_bf16(pa, vb, accO[f], 0, 0, 0);
            }
        }
        __syncthreads();
    }

    // final: out[b][s][h*64+dh] fp32
    #pragma unroll
    for (int f = 0; f < 4; ++f) {
        int dh = f * 16 + (lane & 15);
        #pragma unroll
        for (int r = 0; r < 4; ++r) {
            int qg = q0 + w * 16 + (lane >> 4) * 4 + r;
            float v = accO[f][r] / lrow[r];
            out[((size_t)(b * S_ + qg)) * D_ + h * DH + dh] = v;
        }
    }
}

extern "C" void kernel_launch(void* const* d_in, const int* in_sizes, int n_in,
                              void* d_out, int out_size, void* d_ws, size_t ws_size,
                              hipStream_t stream) {
    const float* x  = (const float*)d_in[0];
    const float* Wq = (const float*)d_in[1];
    const float* bq = (const float*)d_in[2];
    const float* Wk = (const float*)d_in[3];
    const float* bk = (const float*)d_in[4];
    const float* Wv = (const float*)d_in[5];
    const float* bv = (const float*)d_in[6];
    float* out = (float*)d_out;

    __bf16* wsq = (__bf16*)d_ws;
    __bf16* wsk = wsq + (size_t)M_ * D_;
    __bf16* wsv = wsk + (size_t)M_ * D_;

    qkv_gemm<<<dim3(D_ / 128, M_ / 128, 3), 256, 0, stream>>>(
        x, Wq, bq, Wk, bk, Wv, bv, wsq, wsk, wsv);
    attn<<<dim3(S_ / 64, H_, B_), 256, 0, stream>>>(wsq, wsk, wsv, out);
}

// Round 2
// 204.804 us; speedup vs baseline: 1.6834x; 1.6834x over previous
//
#include <hip/hip_runtime.h>
#include <hip/hip_bf16.h>

#define B_ 2
#define S_ 2048
#define D_ 1024
#define H_ 16
#define DH 64
#define M_ (B_*S_)  // 4096
#define NT_ (S_/64) // 32 q/kv tiles per (b,h)

using bf16x8 = __attribute__((ext_vector_type(8))) __bf16;
using f32x4  = __attribute__((ext_vector_type(4))) float;

// combined swizzle key: varies with row bits 0..2 AND 3..5 so both scalar
// transpose writes (row low bits constant per instr) and b128 column reads
// (row low bits varying) spread across banks.  Units: elements, flips the
// 8-element (16B) block index within a 64-element row.
__device__ __forceinline__ int swz(int row) { return ((row ^ (row >> 3)) & 7) << 3; }

__device__ __forceinline__ void glds16(const __bf16* g, __bf16* l) {
#if __has_builtin(__builtin_amdgcn_global_load_lds)
  __builtin_amdgcn_global_load_lds(
      (const __attribute__((address_space(1))) unsigned int*)g,
      (__attribute__((address_space(3))) unsigned int*)l, 16, 0, 0);
#else
  *(bf16x8*)l = *(const bf16x8*)g;
#endif
}

// ---------- convert x fp32 -> bf16, pre-swizzled within 64-col k-groups ----
__global__ __launch_bounds__(256) void conv_x(const float* __restrict__ x,
                                              __bf16* __restrict__ xb) {
  int idx = blockIdx.x * 256 + threadIdx.x;     // one thread per 8 elems
  int m = idx >> 7, k = (idx & 127) * 8;
  float4 a = *(const float4*)&x[(size_t)m * D_ + k];
  float4 b = *(const float4*)&x[(size_t)m * D_ + k + 4];
  bf16x8 o;
  o[0]=(__bf16)a.x; o[1]=(__bf16)a.y; o[2]=(__bf16)a.z; o[3]=(__bf16)a.w;
  o[4]=(__bf16)b.x; o[5]=(__bf16)b.y; o[6]=(__bf16)b.z; o[7]=(__bf16)b.w;
  *(bf16x8*)&xb[(size_t)m * D_ + (k & ~63) + ((k & 63) ^ swz(m))] = o;
}

// ---------- transpose+convert W [k][n] fp32 -> Wt [n][k] bf16 (pre-swz) ----
__global__ __launch_bounds__(256) void conv_w(const float* __restrict__ Wq,
                                              const float* __restrict__ Wk,
                                              const float* __restrict__ Wv,
                                              __bf16* __restrict__ wt) {
  int z = blockIdx.z;
  const float* __restrict__ W = (z == 0) ? Wq : (z == 1) ? Wk : Wv;
  __bf16* __restrict__ Wt = wt + (size_t)z * D_ * D_;
  __shared__ __bf16 Lt[64 * 66];                // [n-local][k-local], pad 66
  int tid = threadIdx.x;
  int k0 = blockIdx.x * 64, n0 = blockIdx.y * 64;
  #pragma unroll
  for (int i = 0; i < 4; ++i) {
    int f4 = i * 256 + tid;                     // 0..1023 float4s
    int r = f4 >> 4, c4 = (f4 & 15) * 4;        // k-row, n-col
    float4 v = *(const float4*)&W[(size_t)(k0 + r) * D_ + n0 + c4];
    Lt[(c4 + 0) * 66 + r] = (__bf16)v.x;
    Lt[(c4 + 1) * 66 + r] = (__bf16)v.y;
    Lt[(c4 + 2) * 66 + r] = (__bf16)v.z;
    Lt[(c4 + 3) * 66 + r] = (__bf16)v.w;
  }
  __syncthreads();
  #pragma unroll
  for (int i = 0; i < 2; ++i) {
    int idx = i * 256 + tid;                    // 0..511 groups of 8
    int n = idx >> 3, kc = (idx & 7) * 8;
    int nf = n0 + n;
    bf16x8 o;
    #pragma unroll
    for (int j = 0; j < 8; ++j) o[j] = Lt[n * 66 + kc + j];
    *(bf16x8*)&Wt[(size_t)nf * D_ + k0 + (kc ^ swz(nf))] = o;
  }
}

// ---------- QKV GEMM, m97-style: 128x128 tile, BK=64, global_load_lds ------
__global__ __launch_bounds__(256) void qkv_gemm(
    const __bf16* __restrict__ xb, const __bf16* __restrict__ wt,
    const float* __restrict__ bq, const float* __restrict__ bk,
    const float* __restrict__ bv, __bf16* __restrict__ qkv) {
  int z = blockIdx.z;
  const __bf16* __restrict__ Wt = wt + (size_t)z * D_ * D_;
  const float* __restrict__ bias = (z == 0) ? bq : (z == 1) ? bk : bv;
  __bf16* __restrict__ out = qkv + (size_t)z * M_ * D_;
  const float scale = (z == 0) ? 0.125f : 1.0f;

  __shared__ __bf16 Al[128 * 64];  // linear; global source is pre-swizzled
  __shared__ __bf16 Bl[128 * 64];

  int tid = threadIdx.x, lane = tid & 63, w = tid >> 6;
  int m0 = blockIdx.y * 128, n0 = blockIdx.x * 128;
  int wr = (w >> 1) * 64, wc = (w & 1) * 64;

  f32x4 acc[4][4] = {};

  for (int kt = 0; kt < D_ / 64; ++kt) {
    int k0 = kt * 64;
    #pragma unroll
    for (int r = 0; r < 4; ++r) {
      int e = (r * 256 + tid) * 8;
      int row = e >> 6, col = e & 63;
      glds16(&xb[(size_t)(m0 + row) * D_ + k0 + col], &Al[e]);
      glds16(&Wt[(size_t)(n0 + row) * D_ + k0 + col], &Bl[e]);
    }
    __syncthreads();

    bf16x8 af[4][2], bfr[4][2];
    #pragma unroll
    for (int mi = 0; mi < 4; ++mi) {
      int row = wr + mi * 16 + (lane & 15);
      int sr = swz(row);
      #pragma unroll
      for (int kk = 0; kk < 2; ++kk)
        af[mi][kk] = *(const bf16x8*)&Al[row * 64 + ((kk * 32 + (lane >> 4) * 8) ^ sr)];
    }
    #pragma unroll
    for (int ni = 0; ni < 4; ++ni) {
      int col = wc + ni * 16 + (lane & 15);
      int sc = swz(col);
      #pragma unroll
      for (int kk = 0; kk < 2; ++kk)
        bfr[ni][kk] = *(const bf16x8*)&Bl[col * 64 + ((kk * 32 + (lane >> 4) * 8) ^ sc)];
    }
    __builtin_amdgcn_s_setprio(1);
    #pragma unroll
    for (int kk = 0; kk < 2; ++kk)
      #pragma unroll
      for (int mi = 0; mi < 4; ++mi)
        #pragma unroll
        for (int ni = 0; ni < 4; ++ni)
          acc[mi][ni] = __builtin_amdgcn_mfma_f32_16x16x32_bf16(
              af[mi][kk], bfr[ni][kk], acc[mi][ni], 0, 0, 0);
    __builtin_amdgcn_s_setprio(0);
    __syncthreads();
  }

  // epilogue: C/D layout col=lane&15, row=(lane>>4)*4+r; out [B][H][S][dh]
  #pragma unroll
  for (int mi = 0; mi < 4; ++mi) {
    #pragma unroll
    for (int ni = 0; ni < 4; ++ni) {
      int col = n0 + wc + ni * 16 + (lane & 15);
      int h = col >> 6, dh = col & 63;
      float bv_ = bias[col];
      #pragma unroll
      for (int r = 0; r < 4; ++r) {
        int row = m0 + wr + mi * 16 + (lane >> 4) * 4 + r;
        int b = row >> 11, s = row & 2047;
        out[((size_t)(b * H_ + h) * S_ + s) * DH + dh] =
            (__bf16)((acc[mi][ni][r] + bv_) * scale);
      }
    }
  }
}

// ---------- flash attention, paired q-tiles for load balance ---------------
__device__ __forceinline__ void attn_tile(
    const bf16x8* aq, f32x4* accO, float* mrow, float* lrow,
    const __bf16* __restrict__ Kl, const __bf16* __restrict__ Vt,
    __bf16* __restrict__ Plw, int lane, int kv0, int qbase, int diag) {
  f32x4 sf[4];
  __builtin_amdgcn_s_setprio(1);
  #pragma unroll
  for (int f = 0; f < 4; ++f) {
    f32x4 zz = {};
    int col = f * 16 + (lane & 15);
    int sc = swz(col);
    #pragma unroll
    for (int kk = 0; kk < 2; ++kk) {
      bf16x8 bk = *(const bf16x8*)&Kl[col * 64 + ((kk * 32 + (lane >> 4) * 8) ^ sc)];
      zz = __builtin_amdgcn_mfma_f32_16x16x32_bf16(aq[kk], bk, zz, 0, 0, 0);
    }
    sf[f] = zz;
  }
  __builtin_amdgcn_s_setprio(0);

  if (diag) {
    #pragma unroll
    for (int f = 0; f < 4; ++f) {
      int kvg = kv0 + f * 16 + (lane & 15);
      #pragma unroll
      for (int r = 0; r < 4; ++r) {
        int qg = qbase + (lane >> 4) * 4 + r;
        if (kvg > qg) sf[f][r] = -1e30f;
      }
    }
  }

  float alpha[4];
  #pragma unroll
  for (int r = 0; r < 4; ++r) {
    float mx = fmaxf(fmaxf(sf[0][r], sf[1][r]), fmaxf(sf[2][r], sf[3][r]));
    #pragma unroll
    for (int off = 8; off >= 1; off >>= 1)
      mx = fmaxf(mx, __shfl_xor(mx, off, 64));
    float mnew = fmaxf(mrow[r], mx);
    alpha[r] = __expf(mrow[r] - mnew);
    mrow[r] = mnew;
    float rs = 0.f;
    #pragma unroll
    for (int f = 0; f < 4; ++f) {
      float p = __expf(sf[f][r] - mnew);
      sf[f][r] = p;
      rs += p;
    }
    #pragma unroll
    for (int off = 8; off >= 1; off >>= 1)
      rs += __shfl_xor(rs, off, 64);
    lrow[r] = lrow[r] * alpha[r] + rs;
  }

  #pragma unroll
  for (int f = 0; f < 4; ++f)
    #pragma unroll
    for (int r = 0; r < 4; ++r) {
      int row = (lane >> 4) * 4 + r;
      Plw[row * 64 + ((f * 16 + (lane & 15)) ^ swz(row))] = (__bf16)sf[f][r];
    }

  #pragma unroll
  for (int f = 0; f < 4; ++f)
    #pragma unroll
    for (int r = 0; r < 4; ++r)
      accO[f][r] *= alpha[r];

  __builtin_amdgcn_s_setprio(1);
  #pragma unroll
  for (int kk = 0; kk < 2; ++kk) {
    int prow = lane & 15;
    bf16x8 pa = *(const bf16x8*)&Plw[prow * 64 + ((kk * 32 + (lane >> 4) * 8) ^ swz(prow))];
    #pragma unroll
    for (int f = 0; f < 4; ++f) {
      int vrow = f * 16 + (lane & 15);
      bf16x8 vb = *(const bf16x8*)&Vt[vrow * 64 + ((kk * 32 + (lane >> 4) * 8) ^ swz(vrow))];
      accO[f] = __builtin_amdgcn_mfma_f32_16x16x32_bf16(pa, vb, accO[f], 0, 0, 0);
    }
  }
  __builtin_amdgcn_s_setprio(0);
}

__device__ __forceinline__ void attn_out(
    const f32x4* accO, const float* lrow, float* __restrict__ out,
    int b, int h, int qbase, int lane) {
  #pragma unroll
  for (int f = 0; f < 4; ++f) {
    int dh = f * 16 + (lane & 15);
    #pragma unroll
    for (int r = 0; r < 4; ++r) {
      int qg = qbase + (lane >> 4) * 4 + r;
      out[((size_t)(b * S_ + qg)) * D_ + h * DH + dh] = accO[f][r] / lrow[r];
    }
  }
}

__global__ __launch_bounds__(256) void attn(
    const __bf16* __restrict__ Q, const __bf16* __restrict__ K,
    const __bf16* __restrict__ V, float* __restrict__ out) {
  __shared__ __bf16 Kl[64 * 64];     // [kv][dh], swizzled
  __shared__ __bf16 Vt[64 * 64];     // [dh][kv], swizzled
  __shared__ __bf16 Pl[4][16 * 64];  // per-wave P

  int tid = threadIdx.x, lane = tid & 63, w = tid >> 6;
  int bx = blockIdx.x, h = blockIdx.y, b = blockIdx.z;
  int qA0 = bx * 64, qB0 = (NT_ - 1 - bx) * 64;   // paired tiles: i and 31-i
  size_t base = ((size_t)(b * H_ + h)) * S_ * DH;
  const __bf16* __restrict__ Qg = Q + base;
  const __bf16* __restrict__ Kg = K + base;
  const __bf16* __restrict__ Vg = V + base;

  bf16x8 aqA[2], aqB[2];
  int qra = qA0 + w * 16 + (lane & 15), qrb = qB0 + w * 16 + (lane & 15);
  #pragma unroll
  for (int kk = 0; kk < 2; ++kk) {
    aqA[kk] = *(const bf16x8*)&Qg[(size_t)qra * DH + kk * 32 + (lane >> 4) * 8];
    aqB[kk] = *(const bf16x8*)&Qg[(size_t)qrb * DH + kk * 32 + (lane >> 4) * 8];
  }

  f32x4 accA[4] = {}, accB[4] = {};
  float mA[4], lA[4], mB[4], lB[4];
  #pragma unroll
  for (int r = 0; r < 4; ++r) { mA[r] = mB[r] = -1e30f; lA[r] = lB[r] = 0.f; }

  const int ktA = bx, ktB = NT_ - 1 - bx;   // ktB >= 16 > ktA always
  for (int kt = 0; kt <= ktB; ++kt) {
    int kv0 = kt * 64;
    #pragma unroll
    for (int i = 0; i < 2; ++i) {
      int e = (i * 256 + tid) * 8;
      int kv = e >> 6, d0 = e & 63;
      bf16x8 k8 = *(const bf16x8*)&Kg[(size_t)(kv0 + kv) * DH + d0];
      *(bf16x8*)&Kl[kv * 64 + (d0 ^ swz(kv))] = k8;
      bf16x8 v8 = *(const bf16x8*)&Vg[(size_t)(kv0 + kv) * DH + d0];
      #pragma unroll
      for (int j = 0; j < 8; ++j) {
        int row = d0 + j;
        Vt[row * 64 + (kv ^ swz(row))] = v8[j];
      }
    }
    __syncthreads();

    attn_tile(aqB, accB, mB, lB, Kl, Vt, Pl[w], lane, kv0, qB0 + w * 16, kt == ktB);
    if (kt <= ktA)
      attn_tile(aqA, accA, mA, lA, Kl, Vt, Pl[w], lane, kv0, qA0 + w * 16, kt == ktA);
    __syncthreads();
  }

  attn_out(accA, lA, out, b, h, qA0 + w * 16, lane);
  attn_out(accB, lB, out, b, h, qB0 + w * 16, lane);
}

extern "C" void kernel_launch(void* const* d_in, const int* in_sizes, int n_in,
                              void* d_out, int out_size, void* d_ws, size_t ws_size,
                              hipStream_t stream) {
  const float* x  = (const float*)d_in[0];
  const float* Wq = (const float*)d_in[1];
  const float* bq = (const float*)d_in[2];
  const float* Wk = (const float*)d_in[3];
  const float* bk = (const float*)d_in[4];
  const float* Wv = (const float*)d_in[5];
  const float* bv = (const float*)d_in[6];
  float* out = (float*)d_out;

  __bf16* xb  = (__bf16*)d_ws;                        // 4M elems (8 MB)
  __bf16* wt  = xb + (size_t)M_ * D_;                 // 3M elems (6 MB)
  __bf16* qkv = wt + (size_t)3 * D_ * D_;             // 12M elems (24 MB)
  __bf16* wsq = qkv;
  __bf16* wsk = qkv + (size_t)M_ * D_;
  __bf16* wsv = qkv + (size_t)2 * M_ * D_;

  conv_x<<<(M_ * (D_ / 8)) / 256, 256, 0, stream>>>(x, xb);
  conv_w<<<dim3(D_ / 64, D_ / 64, 3), 256, 0, stream>>>(Wq, Wk, Wv, wt);
  qkv_gemm<<<dim3(D_ / 128, M_ / 128, 3), 256, 0, stream>>>(xb, wt, bq, bk, bv, qkv);
  attn<<<dim3(NT_ / 2, H_, B_), 256, 0, stream>>>(wsq, wsk, wsv, out);
}